// Round 1
// 253.941 us; speedup vs baseline: 1.0620x; 1.0620x over previous
//
#include <hip/hip_runtime.h>
#include <stdint.h>

#define N_NODES 50000
#define E_EDGES 300000
#define C_CH    256
#define H_HEADS 8
#define NB_SORT 256      // blocks in counting sort
#define CHUNK   1172     // edges per sort block (256*1172 >= 300000)

typedef unsigned short u16;
typedef unsigned int   u32;

typedef __attribute__((ext_vector_type(8))) short  v8s;   // 8 bf16 (MFMA A/B frag)
typedef __attribute__((ext_vector_type(4))) float  v4f;   // MFMA C/D frag

__device__ __forceinline__ float bf2f(u16 v) {
    union { u32 u; float f; } x; x.u = ((u32)v) << 16; return x.f;
}
__device__ __forceinline__ u16 f2bf(float f) {
    union { float f; u32 u; } x; x.f = f;
    u32 r = (x.u + 0x7FFFu + ((x.u >> 16) & 1u)) >> 16;
    return (u16)r;
}
__device__ __forceinline__ void unp2(u32 v, float& lo, float& hi) {
    union { u32 u; float f; } x;
    x.u = v << 16; lo = x.f;
    x.u = v & 0xFFFF0000u; hi = x.f;
}
// async global->LDS, 16 B/lane; LDS dest = wave-uniform base + lane*16
__device__ __forceinline__ void gl_lds16(const u16* g, u16* l) {
    __builtin_amdgcn_global_load_lds(
        (const __attribute__((address_space(1))) void*)g,
        (__attribute__((address_space(3))) void*)l, 16, 0, 0);
}

// ---------------------------------------------------------------------------
// Convert X[50000,256] and Wk,Wv,Wq -> bf16 (Wb packed K,V,Q). One launch.
// ---------------------------------------------------------------------------
__global__ __launch_bounds__(256) void cvt_all(
    const float* __restrict__ x, const float* __restrict__ Wk,
    const float* __restrict__ Wv, const float* __restrict__ Wq,
    u16* __restrict__ Xb, u16* __restrict__ Wb)
{
    int b = blockIdx.x;
    const float* src; u16* dst; int off;
    if (b < 12500) { src = x; dst = Xb; off = b * 1024; }
    else {
        int wb = b - 12500;               // 0..191, 64 blocks per matrix
        int m = (wb < 64) ? 0 : (wb < 128) ? 1 : 2;
        src = (m == 0) ? Wk : (m == 1) ? Wv : Wq;
        dst = Wb + m * 65536; off = (wb & 63) * 1024;
    }
    int i = off + threadIdx.x * 4;
    float4 v = *(const float4*)(src + i);
    ushort4 o;
    o.x = f2bf(v.x); o.y = f2bf(v.y); o.z = f2bf(v.z); o.w = f2bf(v.w);
    *(ushort4*)(dst + i) = o;
}

// ---------------------------------------------------------------------------
// bf16 GEMM: OUT[*,256] = Xb @ W^T + bias.  128x128 tile, BK=64.
// Round-N upgrade vs m97 structure (was latency-bound: 31% HBM, 7% MFMA):
//  (1) double-buffered LDS + 2-phase prefetch: next k-tile's global_load_lds
//      issued BEFORE computing current; one vmcnt(0)+barrier per tile, so
//      32 KB of loads stay in flight across the compute+barrier.
//  (2) T2 XOR swizzle (both-sides, rule #21): linear LDS dest (gl_lds req),
//      source col-group pre-swizzled by (lane&7)^(row&7); frag ds_read_b128
//      applies the same XOR -> bank-conflict-free (was 16-lane bank aliasing).
//  (3) LDS-staged epilogue: C tile + bias packed to the dead As region, then
//      16 B/lane uint4 stores (1 KB/wave contiguous). Old 2 B scalar stores
//      caused 2.27x HBM write amplification (WRITE_SIZE 116 MB vs 51 MB).
// 4 waves x 4x4 16x16x32 frags. grid=(6,391): x = mat*2+nhalf (K,V,Q).
// ---------------------------------------------------------------------------
__global__ __launch_bounds__(256) void gemm3(
    const u16* __restrict__ Xb, const u16* __restrict__ Wb,
    const float* __restrict__ bk, const float* __restrict__ bv,
    const float* __restrict__ bq,
    u16* __restrict__ Kb, u16* __restrict__ Vb, u16* __restrict__ Qb)
{
    __shared__ u16 As[2][128 * 64];   // 2 x 16 KB, row-major, NO pad (gl_lds)
    __shared__ u16 Bs[2][128 * 64];   // 2 x 16 KB
    const int mat = blockIdx.x >> 1, nh = blockIdx.x & 1;
    const int m0 = blockIdx.y * 128;
    if (mat == 2 && m0 >= 256) return;           // Q: only first 2 m-tiles
    const int M = (mat == 2) ? 256 : N_NODES;
    const u16* W = Wb + mat * 65536;
    const float* bias = (mat == 0) ? bk : (mat == 1) ? bv : bq;
    u16* OUT = (mat == 0) ? Kb : (mat == 1) ? Vb : Qb;
    const int n0 = nh * 128;

    const int t = threadIdx.x, lane = t & 63, w = t >> 6;
    const int quad = lane >> 4, l15 = lane & 15;
    const int mq = w & 1, nq = w >> 1;

    v4f acc[16];
#pragma unroll
    for (int i = 0; i < 16; i++) acc[i] = (v4f)(0.0f);

    // staging: wave w covers rows w*32..w*32+31 in 4 chunks of 8 rows.
    // lane -> dest row chunk+lane/8, dest col-group lane&7 (linear LDS).
    // SOURCE col-group is pre-swizzled: sg = (lane&7) ^ (destrow&7), so
    // LDS[row][g] holds global col-group g ^ (row&7)  (XOR involution).
    const int lrow = lane >> 3;               // destrow & 7
    const int sg   = (lane & 7) ^ lrow;       // swizzled source col-group
    const u16* gA = Xb + (size_t)(m0 + w * 32 + lrow) * 256 + sg * 8;
    const u16* gB = W  + (size_t)(n0 + w * 32 + lrow) * 256 + sg * 8;

#define STAGE(bufi, koff) do {                                        \
    gl_lds16(gA + (koff),        &As[bufi][(w * 32 + 0)  * 64]);      \
    gl_lds16(gB + (koff),        &Bs[bufi][(w * 32 + 0)  * 64]);      \
    gl_lds16(gA + 2048 + (koff), &As[bufi][(w * 32 + 8)  * 64]);      \
    gl_lds16(gB + 2048 + (koff), &Bs[bufi][(w * 32 + 8)  * 64]);      \
    gl_lds16(gA + 4096 + (koff), &As[bufi][(w * 32 + 16) * 64]);      \
    gl_lds16(gB + 4096 + (koff), &Bs[bufi][(w * 32 + 16) * 64]);      \
    gl_lds16(gA + 6144 + (koff), &As[bufi][(w * 32 + 24) * 64]);      \
    gl_lds16(gB + 6144 + (koff), &Bs[bufi][(w * 32 + 24) * 64]);      \
} while (0)

    STAGE(0, 0);
    __syncthreads();                          // drain prologue loads
    for (int kt = 0; kt < 4; kt++) {
        const int cur = kt & 1;
        if (kt < 3) STAGE(cur ^ 1, (kt + 1) * 64);   // prefetch next tile
#pragma unroll
        for (int ks = 0; ks < 2; ks++) {
            v8s a[4], b[4];
#pragma unroll
            for (int f = 0; f < 4; f++) {
                int ra = mq * 64 + f * 16 + l15;     // ra&7 == l15&7
                int pg = (ks * 4 + quad) ^ (l15 & 7);
                a[f] = *(const v8s*)(&As[cur][ra * 64 + pg * 8]);
            }
#pragma unroll
            for (int f = 0; f < 4; f++) {
                int rb = nq * 64 + f * 16 + l15;
                int pg = (ks * 4 + quad) ^ (l15 & 7);
                b[f] = *(const v8s*)(&Bs[cur][rb * 64 + pg * 8]);
            }
#pragma unroll
            for (int fm = 0; fm < 4; fm++)
#pragma unroll
                for (int fn = 0; fn < 4; fn++)
                    acc[fm * 4 + fn] = __builtin_amdgcn_mfma_f32_16x16x32_bf16(
                        a[fm], b[fn], acc[fm * 4 + fn], 0, 0, 0);
        }
        __syncthreads();   // drains vmcnt(0): prefetched tile ready; LDS free
    }
#undef STAGE

    // Epilogue: stage C+bias into dead As region (32 KB = 128x128 bf16),
    // then coalesced 16 B/lane stores (full 64 B lines -> no write amp).
    u16* S = &As[0][0];
#pragma unroll
    for (int fn = 0; fn < 4; fn++) {
        int n = nq * 64 + fn * 16 + l15;
        float bi = bias[n0 + n];
#pragma unroll
        for (int fm = 0; fm < 4; fm++) {
#pragma unroll
            for (int r = 0; r < 4; r++) {
                int row = mq * 64 + fm * 16 + quad * 4 + r;
                S[row * 128 + n] = f2bf(acc[fm * 4 + fn][r] + bi);
            }
        }
    }
    __syncthreads();
#pragma unroll
    for (int i = 0; i < 8; i++) {
        int c = i * 256 + t;
        int row = c >> 4;
        int m = m0 + row;
        if (m < M)
            *(uint4*)(OUT + (size_t)m * 256 + n0 + (c & 15) * 8) =
                *(const uint4*)(S + c * 8);
    }
}

// ---------------------------------------------------------------------------
// Counting sort pass 1: per-block LDS histogram of dst -> blockhist[b][256].
// Also builds the anchor adjacency bitmask (rare atomicOr, ~1.5k edges).
// ---------------------------------------------------------------------------
__global__ __launch_bounds__(256) void hist_k(
    const int* __restrict__ src, const int* __restrict__ dst,
    u32* __restrict__ blockhist, u32* __restrict__ inmask)
{
    __shared__ u32 hist[256];
    int t = threadIdx.x, b = blockIdx.x;
    hist[t] = 0;
    __syncthreads();
    int start = b * CHUNK;
    int end = start + CHUNK; if (end > E_EDGES) end = E_EDGES;
    for (int e = start + t; e < end; e += 256) {
        int d = dst[e];
        atomicAdd(&hist[d], 1u);            // LDS atomic: cheap
        int s = src[e];
        if (s < 256) atomicOr(&inmask[d * 8 + (s >> 5)], 1u << (s & 31));
    }
    __syncthreads();
    blockhist[b * 256 + t] = hist[t];
}

// ---------------------------------------------------------------------------
// Counting sort pass 2 (1 block): dst totals, exclusive scan -> dst_off[257],
// per-(block,dst) base offsets -> blockbase[b][d]. Deterministic, no atomics.
// ---------------------------------------------------------------------------
__global__ __launch_bounds__(256) void off_k(
    const u32* __restrict__ blockhist, u32* __restrict__ dst_off,
    u32* __restrict__ blockbase)
{
    __shared__ u32 tmp[256];
    int d = threadIdx.x;
    u32 tot = 0;
    for (int b = 0; b < NB_SORT; b++) tot += blockhist[b * 256 + d];
    tmp[d] = tot;
    __syncthreads();
    for (int off = 1; off < 256; off <<= 1) {
        u32 add = (d >= off) ? tmp[d - off] : 0u;
        __syncthreads();
        tmp[d] += add;
        __syncthreads();
    }
    u32 excl = tmp[d] - tot;
    dst_off[d] = excl;
    if (d == 255) dst_off[256] = tmp[255];
    u32 base = excl;
    for (int b = 0; b < NB_SORT; b++) {
        blockbase[b * 256 + d] = base;
        base += blockhist[b * 256 + d];
    }
}

// ---------------------------------------------------------------------------
// Counting sort pass 3: scatter edge ids using LDS cursors (no global atomics).
// ---------------------------------------------------------------------------
__global__ __launch_bounds__(256) void scatter2_k(
    const int* __restrict__ dst, const u32* __restrict__ blockbase,
    u32* __restrict__ eidx)
{
    __shared__ u32 cur[256];
    int t = threadIdx.x, b = blockIdx.x;
    cur[t] = blockbase[b * 256 + t];
    __syncthreads();
    int start = b * CHUNK;
    int end = start + CHUNK; if (end > E_EDGES) end = E_EDGES;
    for (int e = start + t; e < end; e += 256) {
        u32 pos = atomicAdd(&cur[dst[e]], 1u);   // LDS atomic
        eidx[pos] = (u32)e;
    }
}

// ---------------------------------------------------------------------------
// SPD: 3-level exact-length reachability on the 256-anchor subgraph.
// T[i*256+m] = first k in {1,2,3} with walk of length k from m to i, else 4.
// spd[e] = T[src][dst] for src<256, else 4.  One block.
// ---------------------------------------------------------------------------
__global__ __launch_bounds__(256) void spd_levels(
    const u32* __restrict__ inmask, unsigned char* __restrict__ T)
{
    __shared__ u32 F1[256][8], F2[256][8], F3[256][8];
    int i = threadIdx.x;
#pragma unroll
    for (int w = 0; w < 8; w++) { F1[i][w] = inmask[i * 8 + w]; F2[i][w] = 0; F3[i][w] = 0; }
    __syncthreads();
    for (int w = 0; w < 8; w++) {
        u32 m = F1[i][w];
        while (m) {
            int b = __ffs(m) - 1; m &= m - 1;
            int s = w * 32 + b;
#pragma unroll
            for (int j = 0; j < 8; j++) F2[i][j] |= F1[s][j];
        }
    }
    __syncthreads();
    for (int w = 0; w < 8; w++) {
        u32 m = F1[i][w];
        while (m) {
            int b = __ffs(m) - 1; m &= m - 1;
            int s = w * 32 + b;
#pragma unroll
            for (int j = 0; j < 8; j++) F3[i][j] |= F2[s][j];
        }
    }
    __syncthreads();
    for (int w = 0; w < 8; w++) {
        u32 f1 = F1[i][w], f2 = F2[i][w], f3 = F3[i][w];
#pragma unroll
        for (int g = 0; g < 8; g++) {
            u32 word = 0;
#pragma unroll
            for (int b = 0; b < 4; b++) {
                int bit = g * 4 + b;
                u32 k = ((f1 >> bit) & 1u) ? 1u : ((f2 >> bit) & 1u) ? 2u
                       : ((f3 >> bit) & 1u) ? 3u : 4u;
                word |= k << (8 * b);
            }
            *(u32*)(T + i * 256 + w * 32 + g * 4) = word;
        }
    }
}

// ---------------------------------------------------------------------------
// Fused scores+aggregate: blockIdx = d*8 + part. Lane layout: 2 edges per
// wave (half = lane>>5), 32 lanes x 8 channels each (uint4 = 16 B loads).
// Q[d] loaded once (block-invariant). Per edge: K dot (4-lane shuffle),
// spd bias, exp, V FMA into 8 fp32 acc. Halves merged via shfl_xor 32.
// ---------------------------------------------------------------------------
__global__ __launch_bounds__(256) void agg_k(
    const int* __restrict__ src, const u32* __restrict__ eidx,
    const u32* __restrict__ dst_off, const u16* __restrict__ Qb,
    const u16* __restrict__ Kb, const u16* __restrict__ Vb,
    const unsigned char* __restrict__ T, const float* __restrict__ spd_w,
    float* __restrict__ out, float* __restrict__ denom)
{
    __shared__ float red[4 * 256];
    __shared__ float dred[4 * 8];
    int d    = blockIdx.x >> 3;
    int part = blockIdx.x & 7;
    int t = threadIdx.x, lane = t & 63, wave = t >> 6;
    int half = lane >> 5, sl = lane & 31;
    int h = sl >> 2;                        // head = (sl*8)>>5
    u32 start = dst_off[d], end = dst_off[d + 1];

    uint4 qv = *(const uint4*)(Qb + (size_t)d * 256 + sl * 8);
    float q0,q1,q2,q3,q4,q5,q6,q7;
    unp2(qv.x,q0,q1); unp2(qv.y,q2,q3); unp2(qv.z,q4,q5); unp2(qv.w,q6,q7);
    float sw4 = spd_w[4 * 8 + h];           // spd=4 bias (src>=256, ~98.5% of edges)

    float a0=0.f,a1=0.f,a2=0.f,a3=0.f,a4=0.f,a5=0.f,a6=0.f,a7=0.f,dsum=0.f;
    for (u32 i = start + (u32)(part * 8 + wave * 2 + half); i < end; i += 64) {
        u32 e = eidx[i];                    // 2 distinct edges per wave
        int s = src[e];
        uint4 kv = *(const uint4*)(Kb + (size_t)s * 256 + sl * 8);
        uint4 vv = *(const uint4*)(Vb + (size_t)s * 256 + sl * 8);
        float k0,k1,k2,k3,k4,k5,k6,k7, v0,v1,v2,v3,v4,v5,v6,v7;
        unp2(kv.x,k0,k1); unp2(kv.y,k2,k3); unp2(kv.z,k4,k5); unp2(kv.w,k6,k7);
        unp2(vv.x,v0,v1); unp2(vv.y,v2,v3); unp2(vv.z,v4,v5); unp2(vv.w,v6,v7);
        float p = q0*k0+q1*k1+q2*k2+q3*k3+q4*k4+q5*k5+q6*k6+q7*k7;
        p += __shfl_xor(p, 1);
        p += __shfl_xor(p, 2);              // head dot over 4 lanes x 8 ch
        float bias = (s < 256) ? spd_w[(int)T[s * 256 + d] * 8 + h] : sw4;
        float w = __expf(p * 0.17677669529663689f + bias);
        a0 += w*v0; a1 += w*v1; a2 += w*v2; a3 += w*v3;
        a4 += w*v4; a5 += w*v5; a6 += w*v6; a7 += w*v7;
        if ((sl & 3) == 0) dsum += w;
    }
    a0 += __shfl_xor(a0,32); a1 += __shfl_xor(a1,32);
    a2 += __shfl_xor(a2,32); a3 += __shfl_xor(a3,32);
    a4 += __shfl_xor(a4,32); a5 += __shfl_xor(a5,32);
    a6 += __shfl_xor(a6,32); a7 += __shfl_xor(a7,32);
    dsum += __shfl_xor(dsum,32);
    if (half == 0) {
        *(float4*)(&red[wave * 256 + sl * 8])     = make_float4(a0,a1,a2,a3);
        *(float4*)(&red[wave * 256 + sl * 8 + 4]) = make_float4(a4,a5,a6,a7);
        if ((sl & 3) == 0) dred[wave * 8 + h] = dsum;
    }
    __syncthreads();
    float sAll = red[t] + red[256 + t] + red[512 + t] + red[768 + t];
    atomicAdd(&out[(size_t)d * 256 + t], sAll);
    if (t < 8) {
        float ds = dred[t] + dred[8 + t] + dred[16 + t] + dred[24 + t];
        atomicAdd(&denom[d * 8 + t], ds);
    }
}

// ---------------------------------------------------------------------------
// LayerNorm: h = out/denom (anchors only) + x.  deg is constant per row ->
// cancels exactly under LN; skipped.  One wave per node, fp32 in/out.
// ---------------------------------------------------------------------------
__global__ __launch_bounds__(256) void ln_k(
    const float* __restrict__ x, const float* __restrict__ out,
    const float* __restrict__ denom, const float* __restrict__ gamma,
    const float* __restrict__ beta, float* __restrict__ y)
{
    int n = blockIdx.x * 4 + (threadIdx.x >> 6);
    if (n >= N_NODES) return;
    int lane = threadIdx.x & 63;
    int ch = lane * 4;
    float4 xv = *(const float4*)(x + (size_t)n * 256 + ch);
    float h0 = xv.x, h1 = xv.y, h2 = xv.z, h3 = xv.w;
    if (n < 256) {
        float den = denom[n * 8 + (lane >> 3)];
        float inv = (den > 0.f) ? 1.0f / den : 0.0f;
        const float* op = out + (size_t)n * 256 + ch;
        h0 += op[0] * inv; h1 += op[1] * inv;
        h2 += op[2] * inv; h3 += op[3] * inv;
    }
    float s = h0 + h1 + h2 + h3;
#pragma unroll
    for (int off = 1; off < 64; off <<= 1) s += __shfl_xor(s, off);
    float mu = s * (1.0f / 256.0f);
    float d0 = h0 - mu, d1 = h1 - mu, d2 = h2 - mu, d3 = h3 - mu;
    float q = d0 * d0 + d1 * d1 + d2 * d2 + d3 * d3;
#pragma unroll
    for (int off = 1; off < 64; off <<= 1) q += __shfl_xor(q, off);
    float rstd = rsqrtf(q * (1.0f / 256.0f) + 1e-5f);
    float4 gv = *(const float4*)(gamma + ch);
    float4 bv = *(const float4*)(beta + ch);
    float4 o;
    o.x = d0 * rstd * gv.x + bv.x;
    o.y = d1 * rstd * gv.y + bv.y;
    o.z = d2 * rstd * gv.z + bv.z;
    o.w = d3 * rstd * gv.w + bv.w;
    *(float4*)(y + (size_t)n * 256 + ch) = o;
}

// ---------------------------------------------------------------------------
extern "C" void kernel_launch(void* const* d_in, const int* in_sizes, int n_in,
                              void* d_out, int out_size, void* d_ws, size_t ws_size,
                              hipStream_t stream)
{
    const float* x     = (const float*)d_in[0];
    const int*   src   = (const int*)d_in[1];
    const int*   dst   = (const int*)d_in[2];
    const float* Wq    = (const float*)d_in[3];
    const float* bq    = (const float*)d_in[4];
    const float* Wk    = (const float*)d_in[5];
    const float* bk    = (const float*)d_in[6];
    const float* Wv    = (const float*)d_in[7];
    const float* bv    = (const float*)d_in[8];
    const float* spd_w = (const float*)d_in[9];
    const float* gamma = (const float*)d_in[10];
    const float* beta  = (const float*)d_in[11];
    float* y = (float*)d_out;

    char* ws = (char*)d_ws;
    // --- zeroed region [0, 278528) ---
    float* denom     = (float*)(ws + 0);          //   8192 B
    float* outf      = (float*)(ws + 8192);       // 262144 B
    u32*   inmask    = (u32*)(ws + 270336);       //   8192 B (zero region ends 278528)
    // --- rest (all written before read) ---
    u32*   dst_off   = (u32*)(ws + 278528);       //   1028 B (pad to 280576)
    unsigned char* T = (unsigned char*)(ws + 280576); // 65536 B
    u32*   blockhist = (u32*)(ws + 346112);       // 262144 B
    u32*   blockbase = (u32*)(ws + 608256);       // 262144 B
    u32*   eidx      = (u32*)(ws + 870400);       // 1.2 MB
    u16*   Qb        = (u16*)(ws + 2070400);      // 128 KB
    u16*   Kb        = (u16*)(ws + 2201472);      // 25.6 MB
    u16*   Vb        = (u16*)(ws + 27801472);     // 25.6 MB
    u16*   Xb        = (u16*)(ws + 53401472);     // 50176*512 B = 25.69 MB (pad rows read-only)
    u16*   Wb        = (u16*)(ws + 79091584);     // 3*65536*2 = 384 KB (end ~79.5 MB)

    hipMemsetAsync(d_ws, 0, 278528, stream);

    dim3 blk(256);
    cvt_all<<<dim3(12692), blk, 0, stream>>>(x, Wk, Wv, Wq, Xb, Wb);
    gemm3<<<dim3(6, 391), blk, 0, stream>>>(Xb, Wb, bk, bv, bq, Kb, Vb, Qb);
    hist_k<<<dim3(NB_SORT), blk, 0, stream>>>(src, dst, blockhist, inmask);
    off_k<<<dim3(1), blk, 0, stream>>>(blockhist, dst_off, blockbase);
    spd_levels<<<dim3(1), blk, 0, stream>>>(inmask, T);
    scatter2_k<<<dim3(NB_SORT), blk, 0, stream>>>(dst, blockbase, eidx);
    agg_k<<<dim3(256 * 8), blk, 0, stream>>>(src, eidx, dst_off, Qb, Kb, Vb, T, spd_w, outf, denom);
    ln_k<<<dim3((N_NODES + 3) / 4), blk, 0, stream>>>(x, outf, denom, gamma, beta, y);
}

// Round 2
// 235.629 us; speedup vs baseline: 1.1446x; 1.0777x over previous
//
#include <hip/hip_runtime.h>
#include <stdint.h>

#define N_NODES 50000
#define E_EDGES 300000
#define C_CH    256
#define H_HEADS 8
#define NB2     64       // blocks in counting sort
#define CHUNK2  4688     // edges per sort block (64*4688 >= 300000)
#define NBIN    4096     // 256 dst x 16 src-ranges
#define SRCDIV  3125     // 50000/16 -> src-range = s/3125

typedef unsigned short u16;
typedef unsigned int   u32;

typedef __attribute__((ext_vector_type(8))) short  v8s;   // 8 bf16 (MFMA A/B frag)
typedef __attribute__((ext_vector_type(4))) float  v4f;   // MFMA C/D frag

__device__ __forceinline__ float bf2f(u16 v) {
    union { u32 u; float f; } x; x.u = ((u32)v) << 16; return x.f;
}
__device__ __forceinline__ u16 f2bf(float f) {
    union { float f; u32 u; } x; x.f = f;
    u32 r = (x.u + 0x7FFFu + ((x.u >> 16) & 1u)) >> 16;
    return (u16)r;
}
__device__ __forceinline__ void unp2(u32 v, float& lo, float& hi) {
    union { u32 u; float f; } x;
    x.u = v << 16; lo = x.f;
    x.u = v & 0xFFFF0000u; hi = x.f;
}
// async global->LDS, 16 B/lane; LDS dest = wave-uniform base + lane*16
__device__ __forceinline__ void gl_lds16(const u16* g, u16* l) {
    __builtin_amdgcn_global_load_lds(
        (const __attribute__((address_space(1))) void*)g,
        (__attribute__((address_space(3))) void*)l, 16, 0, 0);
}

// ---------------------------------------------------------------------------
// Convert X[50000,256] and Wk,Wv,Wq -> bf16 (Wb packed K,V,Q). One launch.
// ---------------------------------------------------------------------------
__global__ __launch_bounds__(256) void cvt_all(
    const float* __restrict__ x, const float* __restrict__ Wk,
    const float* __restrict__ Wv, const float* __restrict__ Wq,
    u16* __restrict__ Xb, u16* __restrict__ Wb)
{
    int b = blockIdx.x;
    const float* src; u16* dst; int off;
    if (b < 12500) { src = x; dst = Xb; off = b * 1024; }
    else {
        int wb = b - 12500;               // 0..191, 64 blocks per matrix
        int m = (wb < 64) ? 0 : (wb < 128) ? 1 : 2;
        src = (m == 0) ? Wk : (m == 1) ? Wv : Wq;
        dst = Wb + m * 65536; off = (wb & 63) * 1024;
    }
    int i = off + threadIdx.x * 4;
    float4 v = *(const float4*)(src + i);
    ushort4 o;
    o.x = f2bf(v.x); o.y = f2bf(v.y); o.z = f2bf(v.z); o.w = f2bf(v.w);
    *(ushort4*)(dst + i) = o;
}

// ---------------------------------------------------------------------------
// bf16 GEMM: OUT[*,256] = Xb @ W^T + bias.  128x128 tile, BK=64.
// Double-buffered LDS + 2-phase prefetch; T2 XOR swizzle (both-sides);
// LDS-staged coalesced epilogue. (Round-1: removed gemm3 from top-5.)
// ---------------------------------------------------------------------------
__global__ __launch_bounds__(256) void gemm3(
    const u16* __restrict__ Xb, const u16* __restrict__ Wb,
    const float* __restrict__ bk, const float* __restrict__ bv,
    const float* __restrict__ bq,
    u16* __restrict__ Kb, u16* __restrict__ Vb, u16* __restrict__ Qb)
{
    __shared__ u16 As[2][128 * 64];   // 2 x 16 KB, row-major, NO pad (gl_lds)
    __shared__ u16 Bs[2][128 * 64];   // 2 x 16 KB
    const int mat = blockIdx.x >> 1, nh = blockIdx.x & 1;
    const int m0 = blockIdx.y * 128;
    if (mat == 2 && m0 >= 256) return;           // Q: only first 2 m-tiles
    const int M = (mat == 2) ? 256 : N_NODES;
    const u16* W = Wb + mat * 65536;
    const float* bias = (mat == 0) ? bk : (mat == 1) ? bv : bq;
    u16* OUT = (mat == 0) ? Kb : (mat == 1) ? Vb : Qb;
    const int n0 = nh * 128;

    const int t = threadIdx.x, lane = t & 63, w = t >> 6;
    const int quad = lane >> 4, l15 = lane & 15;
    const int mq = w & 1, nq = w >> 1;

    v4f acc[16];
#pragma unroll
    for (int i = 0; i < 16; i++) acc[i] = (v4f)(0.0f);

    // staging: linear LDS dest; SOURCE col-group pre-swizzled by row (XOR
    // involution) so frag reads apply the same XOR -> conflict-free.
    const int lrow = lane >> 3;               // destrow & 7
    const int sg   = (lane & 7) ^ lrow;       // swizzled source col-group
    const u16* gA = Xb + (size_t)(m0 + w * 32 + lrow) * 256 + sg * 8;
    const u16* gB = W  + (size_t)(n0 + w * 32 + lrow) * 256 + sg * 8;

#define STAGE(bufi, koff) do {                                        \
    gl_lds16(gA + (koff),        &As[bufi][(w * 32 + 0)  * 64]);      \
    gl_lds16(gB + (koff),        &Bs[bufi][(w * 32 + 0)  * 64]);      \
    gl_lds16(gA + 2048 + (koff), &As[bufi][(w * 32 + 8)  * 64]);      \
    gl_lds16(gB + 2048 + (koff), &Bs[bufi][(w * 32 + 8)  * 64]);      \
    gl_lds16(gA + 4096 + (koff), &As[bufi][(w * 32 + 16) * 64]);      \
    gl_lds16(gB + 4096 + (koff), &Bs[bufi][(w * 32 + 16) * 64]);      \
    gl_lds16(gA + 6144 + (koff), &As[bufi][(w * 32 + 24) * 64]);      \
    gl_lds16(gB + 6144 + (koff), &Bs[bufi][(w * 32 + 24) * 64]);      \
} while (0)

    STAGE(0, 0);
    __syncthreads();                          // drain prologue loads
    for (int kt = 0; kt < 4; kt++) {
        const int cur = kt & 1;
        if (kt < 3) STAGE(cur ^ 1, (kt + 1) * 64);   // prefetch next tile
#pragma unroll
        for (int ks = 0; ks < 2; ks++) {
            v8s a[4], b[4];
#pragma unroll
            for (int f = 0; f < 4; f++) {
                int ra = mq * 64 + f * 16 + l15;
                int pg = (ks * 4 + quad) ^ (l15 & 7);
                a[f] = *(const v8s*)(&As[cur][ra * 64 + pg * 8]);
            }
#pragma unroll
            for (int f = 0; f < 4; f++) {
                int rb = nq * 64 + f * 16 + l15;
                int pg = (ks * 4 + quad) ^ (l15 & 7);
                b[f] = *(const v8s*)(&Bs[cur][rb * 64 + pg * 8]);
            }
#pragma unroll
            for (int fm = 0; fm < 4; fm++)
#pragma unroll
                for (int fn = 0; fn < 4; fn++)
                    acc[fm * 4 + fn] = __builtin_amdgcn_mfma_f32_16x16x32_bf16(
                        a[fm], b[fn], acc[fm * 4 + fn], 0, 0, 0);
        }
        __syncthreads();   // drains vmcnt(0): prefetched tile ready; LDS free
    }
#undef STAGE

    // Epilogue: stage C+bias into dead As region, coalesced uint4 stores.
    u16* S = &As[0][0];
#pragma unroll
    for (int fn = 0; fn < 4; fn++) {
        int n = nq * 64 + fn * 16 + l15;
        float bi = bias[n0 + n];
#pragma unroll
        for (int fm = 0; fm < 4; fm++) {
#pragma unroll
            for (int r = 0; r < 4; r++) {
                int row = mq * 64 + fm * 16 + quad * 4 + r;
                S[row * 128 + n] = f2bf(acc[fm * 4 + fn][r] + bi);
            }
        }
    }
    __syncthreads();
#pragma unroll
    for (int i = 0; i < 8; i++) {
        int c = i * 256 + t;
        int row = c >> 4;
        int m = m0 + row;
        if (m < M)
            *(uint4*)(OUT + (size_t)m * 256 + n0 + (c & 15) * 8) =
                *(const uint4*)(S + c * 8);
    }
}

// ---------------------------------------------------------------------------
// Sort pass 1: per-block LDS histogram over 4096 (dst, src-range) bins.
// Also accumulates global bin totals (bintot, zeroed) and the anchor
// adjacency bitmask.
// ---------------------------------------------------------------------------
__global__ __launch_bounds__(256) void hist_k(
    const int* __restrict__ src, const int* __restrict__ dst,
    u32* __restrict__ blockhist, u32* __restrict__ bintot,
    u32* __restrict__ inmask)
{
    __shared__ u32 hist[NBIN];
    int t = threadIdx.x, b = blockIdx.x;
#pragma unroll
    for (int j = 0; j < 16; j++) hist[t + j * 256] = 0;
    __syncthreads();
    int start = b * CHUNK2;
    int end = start + CHUNK2; if (end > E_EDGES) end = E_EDGES;
    for (int e = start + t; e < end; e += 256) {
        int d = dst[e], s = src[e];
        atomicAdd(&hist[d * 16 + s / SRCDIV], 1u);     // LDS atomic
        if (s < 256) atomicOr(&inmask[d * 8 + (s >> 5)], 1u << (s & 31));
    }
    __syncthreads();
#pragma unroll
    for (int j = 0; j < 16; j++) {
        int bin = t + j * 256;
        u32 h = hist[bin];
        blockhist[b * NBIN + bin] = h;
        if (h) atomicAdd(&bintot[bin], h);
    }
}

// ---------------------------------------------------------------------------
// Sort pass 2 (1 block): exclusive scan of bintot[4096] -> bin_off[4097].
// Per-thread 16 sequential bins + block scan of thread sums.
// ---------------------------------------------------------------------------
__global__ __launch_bounds__(256) void scan_k(
    const u32* __restrict__ bintot, u32* __restrict__ bin_off)
{
    __shared__ u32 tsum[256];
    int t = threadIdx.x;
    u32 loc[16]; u32 a = 0;
#pragma unroll
    for (int j = 0; j < 16; j++) { loc[j] = bintot[t * 16 + j]; a += loc[j]; }
    tsum[t] = a;
    __syncthreads();
    for (int off = 1; off < 256; off <<= 1) {
        u32 add = (t >= off) ? tsum[t - off] : 0u;
        __syncthreads();
        tsum[t] += add;
        __syncthreads();
    }
    u32 base = tsum[t] - a;
#pragma unroll
    for (int j = 0; j < 16; j++) { bin_off[t * 16 + j] = base; base += loc[j]; }
    if (t == 255) bin_off[NBIN] = base;
}

// ---------------------------------------------------------------------------
// Sort pass 3 (16 blocks): per-(sortblock,bin) base = bin_off + block prefix.
// ---------------------------------------------------------------------------
__global__ __launch_bounds__(256) void base_k(
    const u32* __restrict__ blockhist, const u32* __restrict__ bin_off,
    u32* __restrict__ blockbase)
{
    int bin = blockIdx.x * 256 + threadIdx.x;
    u32 run = bin_off[bin];
    for (int b = 0; b < NB2; b++) {
        blockbase[b * NBIN + bin] = run;
        run += blockhist[b * NBIN + bin];
    }
}

// ---------------------------------------------------------------------------
// Sort pass 4: scatter SRC VALUES (not edge ids — kills one dependent load
// level in agg) into (dst, src-range) buckets using LDS cursors.
// ---------------------------------------------------------------------------
__global__ __launch_bounds__(256) void scatter2_k(
    const int* __restrict__ src, const int* __restrict__ dst,
    const u32* __restrict__ blockbase, u32* __restrict__ ssrc)
{
    __shared__ u32 cur[NBIN];
    int t = threadIdx.x, b = blockIdx.x;
#pragma unroll
    for (int j = 0; j < 16; j++)
        cur[t + j * 256] = blockbase[b * NBIN + t + j * 256];
    __syncthreads();
    int start = b * CHUNK2;
    int end = start + CHUNK2; if (end > E_EDGES) end = E_EDGES;
    for (int e = start + t; e < end; e += 256) {
        int s = src[e];
        int bin = dst[e] * 16 + s / SRCDIV;
        u32 pos = atomicAdd(&cur[bin], 1u);   // LDS atomic
        ssrc[pos] = (u32)s;
    }
}

// ---------------------------------------------------------------------------
// SPD: 3-level exact-length reachability on the 256-anchor subgraph.
// ---------------------------------------------------------------------------
__global__ __launch_bounds__(256) void spd_levels(
    const u32* __restrict__ inmask, unsigned char* __restrict__ T)
{
    __shared__ u32 F1[256][8], F2[256][8], F3[256][8];
    int i = threadIdx.x;
#pragma unroll
    for (int w = 0; w < 8; w++) { F1[i][w] = inmask[i * 8 + w]; F2[i][w] = 0; F3[i][w] = 0; }
    __syncthreads();
    for (int w = 0; w < 8; w++) {
        u32 m = F1[i][w];
        while (m) {
            int b = __ffs(m) - 1; m &= m - 1;
            int s = w * 32 + b;
#pragma unroll
            for (int j = 0; j < 8; j++) F2[i][j] |= F1[s][j];
        }
    }
    __syncthreads();
    for (int w = 0; w < 8; w++) {
        u32 m = F1[i][w];
        while (m) {
            int b = __ffs(m) - 1; m &= m - 1;
            int s = w * 32 + b;
#pragma unroll
            for (int j = 0; j < 8; j++) F3[i][j] |= F2[s][j];
        }
    }
    __syncthreads();
    for (int w = 0; w < 8; w++) {
        u32 f1 = F1[i][w], f2 = F2[i][w], f3 = F3[i][w];
#pragma unroll
        for (int g = 0; g < 8; g++) {
            u32 word = 0;
#pragma unroll
            for (int b = 0; b < 4; b++) {
                int bit = g * 4 + b;
                u32 k = ((f1 >> bit) & 1u) ? 1u : ((f2 >> bit) & 1u) ? 2u
                       : ((f3 >> bit) & 1u) ? 3u : 4u;
                word |= k << (8 * b);
            }
            *(u32*)(T + i * 256 + w * 32 + g * 4) = word;
        }
    }
}

// ---------------------------------------------------------------------------
// Fused scores+aggregate.  blockIdx = d*16 + src-range p -> each block's K/V
// gather stays inside a 3.2 MB src window; blockIdx%8 == p%8 pins a window
// pair per XCD L2 (was: random over 51 MB -> 147 MB FETCH).  2-deep pipeline:
// src 2 iters ahead, K/V rows 1 iter ahead.  Lane layout: 2 edges/wave
// (half = lane>>5), 32 lanes x 8 ch (uint4).  Halves merged via shfl_xor 32.
// ---------------------------------------------------------------------------
__global__ __launch_bounds__(256) void agg_k(
    const u32* __restrict__ ssrc, const u32* __restrict__ bin_off,
    const u16* __restrict__ Qb, const u16* __restrict__ Kb,
    const u16* __restrict__ Vb, const unsigned char* __restrict__ T,
    const float* __restrict__ spd_w, float* __restrict__ out,
    float* __restrict__ denom)
{
    __shared__ float red[4 * 256];
    __shared__ float dred[4 * 8];
    int bid = blockIdx.x;
    int d = bid >> 4;
    int t = threadIdx.x, lane = t & 63, wave = t >> 6;
    int half = lane >> 5, sl = lane & 31;
    int h = sl >> 2;                        // head = (sl*8)>>5
    u32 start = bin_off[bid], end = bin_off[bid + 1];

    uint4 qv = *(const uint4*)(Qb + (size_t)d * 256 + sl * 8);
    float q0,q1,q2,q3,q4,q5,q6,q7;
    unp2(qv.x,q0,q1); unp2(qv.y,q2,q3); unp2(qv.z,q4,q5); unp2(qv.w,q6,q7);
    float sw4 = spd_w[4 * 8 + h];           // spd=4 bias (src>=256, ~98.5%)

    float a0=0.f,a1=0.f,a2=0.f,a3=0.f,a4=0.f,a5=0.f,a6=0.f,a7=0.f,dsum=0.f;

    u32 i = start + (u32)(wave * 2 + half);  // 8 slots, stride 8
    int s_c = 0, s_n = 0;
    uint4 kv_c = make_uint4(0,0,0,0), vv_c = kv_c;
    if (i < end) {
        s_c = (int)ssrc[i];
        kv_c = *(const uint4*)(Kb + (size_t)s_c * 256 + sl * 8);
        vv_c = *(const uint4*)(Vb + (size_t)s_c * 256 + sl * 8);
        if (i + 8 < end) s_n = (int)ssrc[i + 8];
    }
    while (i < end) {
        u32 inx = i + 8;
        uint4 kv_n = kv_c, vv_n = vv_c;
        if (inx < end) {                    // issue next row loads (addr ready)
            kv_n = *(const uint4*)(Kb + (size_t)s_n * 256 + sl * 8);
            vv_n = *(const uint4*)(Vb + (size_t)s_n * 256 + sl * 8);
        }
        int s_nn = (inx + 8 < end) ? (int)ssrc[inx + 8] : 0;
        float k0,k1,k2,k3,k4,k5,k6,k7, v0,v1,v2,v3,v4,v5,v6,v7;
        unp2(kv_c.x,k0,k1); unp2(kv_c.y,k2,k3); unp2(kv_c.z,k4,k5); unp2(kv_c.w,k6,k7);
        unp2(vv_c.x,v0,v1); unp2(vv_c.y,v2,v3); unp2(vv_c.z,v4,v5); unp2(vv_c.w,v6,v7);
        float p = q0*k0+q1*k1+q2*k2+q3*k3+q4*k4+q5*k5+q6*k6+q7*k7;
        p += __shfl_xor(p, 1);
        p += __shfl_xor(p, 2);              // head dot over 4 lanes x 8 ch
        float bias = (s_c < 256) ? spd_w[(int)T[s_c * 256 + d] * 8 + h] : sw4;
        float wgt = __expf(p * 0.17677669529663689f + bias);
        a0 += wgt*v0; a1 += wgt*v1; a2 += wgt*v2; a3 += wgt*v3;
        a4 += wgt*v4; a5 += wgt*v5; a6 += wgt*v6; a7 += wgt*v7;
        if ((sl & 3) == 0) dsum += wgt;
        i = inx; s_c = s_n; s_n = s_nn; kv_c = kv_n; vv_c = vv_n;
    }
    a0 += __shfl_xor(a0,32); a1 += __shfl_xor(a1,32);
    a2 += __shfl_xor(a2,32); a3 += __shfl_xor(a3,32);
    a4 += __shfl_xor(a4,32); a5 += __shfl_xor(a5,32);
    a6 += __shfl_xor(a6,32); a7 += __shfl_xor(a7,32);
    dsum += __shfl_xor(dsum,32);
    if (half == 0) {
        *(float4*)(&red[wave * 256 + sl * 8])     = make_float4(a0,a1,a2,a3);
        *(float4*)(&red[wave * 256 + sl * 8 + 4]) = make_float4(a4,a5,a6,a7);
        if ((sl & 3) == 0) dred[wave * 8 + h] = dsum;
    }
    __syncthreads();
    float sAll = red[t] + red[256 + t] + red[512 + t] + red[768 + t];
    atomicAdd(&out[(size_t)d * 256 + t], sAll);
    if (t < 8) {
        float ds = dred[t] + dred[8 + t] + dred[16 + t] + dred[24 + t];
        atomicAdd(&denom[d * 8 + t], ds);
    }
}

// ---------------------------------------------------------------------------
// LayerNorm: h = out/denom (anchors only) + x.  deg is constant per row ->
// cancels exactly under LN; skipped.  One wave per node, fp32 in/out.
// ---------------------------------------------------------------------------
__global__ __launch_bounds__(256) void ln_k(
    const float* __restrict__ x, const float* __restrict__ out,
    const float* __restrict__ denom, const float* __restrict__ gamma,
    const float* __restrict__ beta, float* __restrict__ y)
{
    int n = blockIdx.x * 4 + (threadIdx.x >> 6);
    if (n >= N_NODES) return;
    int lane = threadIdx.x & 63;
    int ch = lane * 4;
    float4 xv = *(const float4*)(x + (size_t)n * 256 + ch);
    float h0 = xv.x, h1 = xv.y, h2 = xv.z, h3 = xv.w;
    if (n < 256) {
        float den = denom[n * 8 + (lane >> 3)];
        float inv = (den > 0.f) ? 1.0f / den : 0.0f;
        const float* op = out + (size_t)n * 256 + ch;
        h0 += op[0] * inv; h1 += op[1] * inv;
        h2 += op[2] * inv; h3 += op[3] * inv;
    }
    float s = h0 + h1 + h2 + h3;
#pragma unroll
    for (int off = 1; off < 64; off <<= 1) s += __shfl_xor(s, off);
    float mu = s * (1.0f / 256.0f);
    float d0 = h0 - mu, d1 = h1 - mu, d2 = h2 - mu, d3 = h3 - mu;
    float q = d0 * d0 + d1 * d1 + d2 * d2 + d3 * d3;
#pragma unroll
    for (int off = 1; off < 64; off <<= 1) q += __shfl_xor(q, off);
    float rstd = rsqrtf(q * (1.0f / 256.0f) + 1e-5f);
    float4 gv = *(const float4*)(gamma + ch);
    float4 bv = *(const float4*)(beta + ch);
    float4 o;
    o.x = d0 * rstd * gv.x + bv.x;
    o.y = d1 * rstd * gv.y + bv.y;
    o.z = d2 * rstd * gv.z + bv.z;
    o.w = d3 * rstd * gv.w + bv.w;
    *(float4*)(y + (size_t)n * 256 + ch) = o;
}

// ---------------------------------------------------------------------------
extern "C" void kernel_launch(void* const* d_in, const int* in_sizes, int n_in,
                              void* d_out, int out_size, void* d_ws, size_t ws_size,
                              hipStream_t stream)
{
    const float* x     = (const float*)d_in[0];
    const int*   src   = (const int*)d_in[1];
    const int*   dst   = (const int*)d_in[2];
    const float* Wq    = (const float*)d_in[3];
    const float* bq    = (const float*)d_in[4];
    const float* Wk    = (const float*)d_in[5];
    const float* bk    = (const float*)d_in[6];
    const float* Wv    = (const float*)d_in[7];
    const float* bv    = (const float*)d_in[8];
    const float* spd_w = (const float*)d_in[9];
    const float* gamma = (const float*)d_in[10];
    const float* beta  = (const float*)d_in[11];
    float* y = (float*)d_out;

    char* ws = (char*)d_ws;
    // --- zeroed region [0, 294912) ---
    float* denom     = (float*)(ws + 0);          //   8192 B
    float* outf      = (float*)(ws + 8192);       // 262144 B
    u32*   inmask    = (u32*)(ws + 270336);       //   8192 B
    u32*   bintot    = (u32*)(ws + 278528);       //  16384 B (zero ends 294912)
    // --- rest (all written before read) ---
    u32*   bin_off   = (u32*)(ws + 294912);       //  16388 B (pad to 311552)
    unsigned char* T = (unsigned char*)(ws + 311552); // 65536 B -> 377088
    u32*   blockhist = (u32*)(ws + 377088);       // 64*4096*4 = 1 MB -> 1425664
    u32*   blockbase = (u32*)(ws + 1425664);      // 1 MB -> 2474240
    u32*   ssrc      = (u32*)(ws + 2474240);      // 1.2 MB (pad) -> 3676416
    u16*   Qb        = (u16*)(ws + 3676416);      // 128 KB -> 3807488
    u16*   Kb        = (u16*)(ws + 3807488);      // 25.6 MB -> 29407488
    u16*   Vb        = (u16*)(ws + 29407488);     // 25.6 MB -> 55007488
    u16*   Xb        = (u16*)(ws + 55007488);     // 50176*512 B -> 80697600
    u16*   Wb        = (u16*)(ws + 80697600);     // 384 KB (end ~81.1 MB)

    hipMemsetAsync(d_ws, 0, 294912, stream);

    dim3 blk(256);
    cvt_all<<<dim3(12692), blk, 0, stream>>>(x, Wk, Wv, Wq, Xb, Wb);
    gemm3<<<dim3(6, 391), blk, 0, stream>>>(Xb, Wb, bk, bv, bq, Kb, Vb, Qb);
    hist_k<<<dim3(NB2), blk, 0, stream>>>(src, dst, blockhist, bintot, inmask);
    scan_k<<<dim3(1), blk, 0, stream>>>(bintot, bin_off);
    base_k<<<dim3(16), blk, 0, stream>>>(blockhist, bin_off, blockbase);
    spd_levels<<<dim3(1), blk, 0, stream>>>(inmask, T);
    scatter2_k<<<dim3(NB2), blk, 0, stream>>>(src, dst, blockbase, ssrc);
    agg_k<<<dim3(NBIN), blk, 0, stream>>>(ssrc, bin_off, Qb, Kb, Vb, T, spd_w, outf, denom);
    ln_k<<<dim3((N_NODES + 3) / 4), blk, 0, stream>>>(x, outf, denom, gamma, beta, y);
}

// Round 3
// 222.650 us; speedup vs baseline: 1.2113x; 1.0583x over previous
//
#include <hip/hip_runtime.h>
#include <stdint.h>

#define N_NODES 50000
#define E_EDGES 300000
#define C_CH    256
#define H_HEADS 8
#define NB2     64       // blocks in counting sort
#define CHUNK2  4688     // edges per sort block (64*4688 >= 300000)
#define NBIN    4096     // 256 dst x 16 src-ranges
#define SRCDIV  3125     // 50000/16 -> src-range = s/3125

typedef unsigned short u16;
typedef unsigned int   u32;

typedef __attribute__((ext_vector_type(8))) short  v8s;   // 8 bf16 (MFMA A/B frag)
typedef __attribute__((ext_vector_type(4))) float  v4f;   // MFMA C/D frag

__device__ __forceinline__ float bf2f(u16 v) {
    union { u32 u; float f; } x; x.u = ((u32)v) << 16; return x.f;
}
__device__ __forceinline__ u16 f2bf(float f) {
    union { float f; u32 u; } x; x.f = f;
    u32 r = (x.u + 0x7FFFu + ((x.u >> 16) & 1u)) >> 16;
    return (u16)r;
}
__device__ __forceinline__ void unp2(u32 v, float& lo, float& hi) {
    union { u32 u; float f; } x;
    x.u = v << 16; lo = x.f;
    x.u = v & 0xFFFF0000u; hi = x.f;
}
// async global->LDS, 16 B/lane; LDS dest = wave-uniform base + lane*16
__device__ __forceinline__ void gl_lds16(const u16* g, u16* l) {
    __builtin_amdgcn_global_load_lds(
        (const __attribute__((address_space(1))) void*)g,
        (__attribute__((address_space(3))) void*)l, 16, 0, 0);
}

// ---------------------------------------------------------------------------
// Convert X[50000,256] and Wk,Wv,Wq -> bf16 (Wb packed K,V,Q). One launch.
// ---------------------------------------------------------------------------
__global__ __launch_bounds__(256) void cvt_all(
    const float* __restrict__ x, const float* __restrict__ Wk,
    const float* __restrict__ Wv, const float* __restrict__ Wq,
    u16* __restrict__ Xb, u16* __restrict__ Wb)
{
    int b = blockIdx.x;
    const float* src; u16* dst; int off;
    if (b < 12500) { src = x; dst = Xb; off = b * 1024; }
    else {
        int wb = b - 12500;               // 0..191, 64 blocks per matrix
        int m = (wb < 64) ? 0 : (wb < 128) ? 1 : 2;
        src = (m == 0) ? Wk : (m == 1) ? Wv : Wq;
        dst = Wb + m * 65536; off = (wb & 63) * 1024;
    }
    int i = off + threadIdx.x * 4;
    float4 v = *(const float4*)(src + i);
    ushort4 o;
    o.x = f2bf(v.x); o.y = f2bf(v.y); o.z = f2bf(v.z); o.w = f2bf(v.w);
    *(ushort4*)(dst + i) = o;
}

// ---------------------------------------------------------------------------
// bf16 GEMM: OUT[*,256] = Xb @ W^T + bias.  128x128 tile, BK=32, 8 k-tiles.
// Round-3: was 39.5us @ 13.9% occupancy (64KB LDS -> 2 blocks/CU, drain
// barely overlapped).  BK=32 dbuf -> 32KB LDS -> 4-5 blocks/CU; fragment
// read = contiguous 1KB wave-read (conflict-free, no swizzle needed);
// bijective XCD-chunked swizzle (m-tile-major) for A-tile L2 locality.
// ---------------------------------------------------------------------------
__global__ __launch_bounds__(256, 4) void gemm3(
    const u16* __restrict__ Xb, const u16* __restrict__ Wb,
    const float* __restrict__ bk, const float* __restrict__ bv,
    const float* __restrict__ bq,
    u16* __restrict__ Kb, u16* __restrict__ Vb, u16* __restrict__ Qb)
{
    __shared__ u16 buf[4][128 * 32];   // A dbuf = buf[0,1], B dbuf = buf[2,3]
    // bijective XCD-chunked swizzle (8 XCDs, round-robin dispatch id%8):
    // each XCD gets a contiguous wgid chunk; wgid ordered m-tile-major so
    // all 6 (mat,nh) blocks of an m-tile share one XCD L2.
    const int nwg = 2346, q = nwg >> 3, r = nwg & 7;   // q=293, r=2
    int xcd = blockIdx.x & 7, pos = blockIdx.x >> 3;
    int wgid = (xcd < r ? xcd * (q + 1) : r * (q + 1) + (xcd - r) * q) + pos;
    const int mt = wgid / 6, j6 = wgid % 6;
    const int mat = j6 >> 1, nh = j6 & 1;
    const int m0 = mt * 128;
    if (mat == 2 && m0 >= 256) return;           // Q: only first 2 m-tiles
    const int M = (mat == 2) ? 256 : N_NODES;
    const u16* W = Wb + mat * 65536;
    const float* bias = (mat == 0) ? bk : (mat == 1) ? bv : bq;
    u16* OUT = (mat == 0) ? Kb : (mat == 1) ? Vb : Qb;
    const int n0 = nh * 128;

    const int t = threadIdx.x, lane = t & 63, w = t >> 6;
    const int quad = lane >> 4, l15 = lane & 15;
    const int mq = w & 1, nq = w >> 1;

    v4f acc[16];
#pragma unroll
    for (int i = 0; i < 16; i++) acc[i] = (v4f)(0.0f);

    // staging (per wave, per k-tile): rows w*32..+31 in 2 chunks of 16 rows,
    // lane -> row chunk + lane/4, col-group (lane&3)*8 (16 B).  Linear both
    // sides; the BK=32 frag read is a contiguous 1 KB region -> no swizzle.
    const int lrow = lane >> 2;               // 0..15
    const int scol = (lane & 3) * 8;
    const u16* gA = Xb + (size_t)(m0 + w * 32 + lrow) * 256 + scol;
    const u16* gB = W  + (size_t)(n0 + w * 32 + lrow) * 256 + scol;

#define STAGE(bi, koff) do {                                          \
    gl_lds16(gA + (koff),            &buf[bi][(w * 32) * 32]);        \
    gl_lds16(gA + 16 * 256 + (koff), &buf[bi][(w * 32 + 16) * 32]);   \
    gl_lds16(gB + (koff),            &buf[2 + (bi)][(w * 32) * 32]);  \
    gl_lds16(gB + 16 * 256 + (koff), &buf[2 + (bi)][(w * 32 + 16) * 32]); \
} while (0)

    STAGE(0, 0);
    __syncthreads();                          // drain prologue loads
    for (int kt = 0; kt < 8; kt++) {
        const int cur = kt & 1;
        if (kt < 7) STAGE(cur ^ 1, (kt + 1) * 32);   // prefetch next tile
        v8s a[4], b[4];
#pragma unroll
        for (int f = 0; f < 4; f++)
            a[f] = *(const v8s*)(&buf[cur][(mq * 64 + f * 16 + l15) * 32 + quad * 8]);
#pragma unroll
        for (int f = 0; f < 4; f++)
            b[f] = *(const v8s*)(&buf[2 + cur][(nq * 64 + f * 16 + l15) * 32 + quad * 8]);
#pragma unroll
        for (int fm = 0; fm < 4; fm++)
#pragma unroll
            for (int fn = 0; fn < 4; fn++)
                acc[fm * 4 + fn] = __builtin_amdgcn_mfma_f32_16x16x32_bf16(
                    a[fm], b[fn], acc[fm * 4 + fn], 0, 0, 0);
        __syncthreads();   // drains vmcnt(0): prefetched tile ready; LDS free
    }
#undef STAGE

    // Epilogue: stage C+bias into LDS (32 KB = all 4 buffers), coalesced
    // uint4 stores (full 64 B lines -> no write amplification).
    u16* S = &buf[0][0];
#pragma unroll
    for (int fn = 0; fn < 4; fn++) {
        int n = nq * 64 + fn * 16 + l15;
        float bi = bias[n0 + n];
#pragma unroll
        for (int fm = 0; fm < 4; fm++) {
#pragma unroll
            for (int r2 = 0; r2 < 4; r2++) {
                int row = mq * 64 + fm * 16 + quad * 4 + r2;
                S[row * 128 + n] = f2bf(acc[fm * 4 + fn][r2] + bi);
            }
        }
    }
    __syncthreads();
#pragma unroll
    for (int i = 0; i < 8; i++) {
        int c = i * 256 + t;
        int row = c >> 4;
        int m = m0 + row;
        if (m < M)
            *(uint4*)(OUT + (size_t)m * 256 + n0 + (c & 15) * 8) =
                *(const uint4*)(S + c * 8);
    }
}

// ---------------------------------------------------------------------------
// Sort pass 1: per-block LDS histogram over 4096 (dst, src-range) bins.
// Also accumulates global bin totals (bintot, zeroed) and the anchor
// adjacency bitmask.
// ---------------------------------------------------------------------------
__global__ __launch_bounds__(256) void hist_k(
    const int* __restrict__ src, const int* __restrict__ dst,
    u32* __restrict__ blockhist, u32* __restrict__ bintot,
    u32* __restrict__ inmask)
{
    __shared__ u32 hist[NBIN];
    int t = threadIdx.x, b = blockIdx.x;
#pragma unroll
    for (int j = 0; j < 16; j++) hist[t + j * 256] = 0;
    __syncthreads();
    int start = b * CHUNK2;
    int end = start + CHUNK2; if (end > E_EDGES) end = E_EDGES;
    for (int e = start + t; e < end; e += 256) {
        int d = dst[e], s = src[e];
        atomicAdd(&hist[d * 16 + s / SRCDIV], 1u);     // LDS atomic
        if (s < 256) atomicOr(&inmask[d * 8 + (s >> 5)], 1u << (s & 31));
    }
    __syncthreads();
#pragma unroll
    for (int j = 0; j < 16; j++) {
        int bin = t + j * 256;
        u32 h = hist[bin];
        blockhist[b * NBIN + bin] = h;
        if (h) atomicAdd(&bintot[bin], h);
    }
}

// ---------------------------------------------------------------------------
// Sort pass 2 (1 block): exclusive scan of bintot[4096] -> bin_off[4097].
// ---------------------------------------------------------------------------
__global__ __launch_bounds__(256) void scan_k(
    const u32* __restrict__ bintot, u32* __restrict__ bin_off)
{
    __shared__ u32 tsum[256];
    int t = threadIdx.x;
    u32 loc[16]; u32 a = 0;
#pragma unroll
    for (int j = 0; j < 16; j++) { loc[j] = bintot[t * 16 + j]; a += loc[j]; }
    tsum[t] = a;
    __syncthreads();
    for (int off = 1; off < 256; off <<= 1) {
        u32 add = (t >= off) ? tsum[t - off] : 0u;
        __syncthreads();
        tsum[t] += add;
        __syncthreads();
    }
    u32 base = tsum[t] - a;
#pragma unroll
    for (int j = 0; j < 16; j++) { bin_off[t * 16 + j] = base; base += loc[j]; }
    if (t == 255) bin_off[NBIN] = base;
}

// ---------------------------------------------------------------------------
// Sort pass 3 (16 blocks): per-(sortblock,bin) base = bin_off + block prefix.
// Round-3: prefetch all 64 histogram values into regs (independent loads,
// one latency) then prefix in regs — was 64 dependent loads at 0.25 wave/CU.
// ---------------------------------------------------------------------------
__global__ __launch_bounds__(256) void base_k(
    const u32* __restrict__ blockhist, const u32* __restrict__ bin_off,
    u32* __restrict__ blockbase)
{
    int bin = blockIdx.x * 256 + threadIdx.x;
    u32 h[NB2];
#pragma unroll
    for (int b = 0; b < NB2; b++) h[b] = blockhist[b * NBIN + bin];
    u32 run = bin_off[bin];
#pragma unroll
    for (int b = 0; b < NB2; b++) {
        blockbase[b * NBIN + bin] = run;
        run += h[b];
    }
}

// ---------------------------------------------------------------------------
// Sort pass 4: scatter SRC VALUES (not edge ids — kills one dependent load
// level in agg) into (dst, src-range) buckets using LDS cursors.
// ---------------------------------------------------------------------------
__global__ __launch_bounds__(256) void scatter2_k(
    const int* __restrict__ src, const int* __restrict__ dst,
    const u32* __restrict__ blockbase, u32* __restrict__ ssrc)
{
    __shared__ u32 cur[NBIN];
    int t = threadIdx.x, b = blockIdx.x;
#pragma unroll
    for (int j = 0; j < 16; j++)
        cur[t + j * 256] = blockbase[b * NBIN + t + j * 256];
    __syncthreads();
    int start = b * CHUNK2;
    int end = start + CHUNK2; if (end > E_EDGES) end = E_EDGES;
    for (int e = start + t; e < end; e += 256) {
        int s = src[e];
        int bin = dst[e] * 16 + s / SRCDIV;
        u32 pos = atomicAdd(&cur[bin], 1u);   // LDS atomic
        ssrc[pos] = (u32)s;
    }
}

// ---------------------------------------------------------------------------
// SPD: 3-level exact-length reachability on the 256-anchor subgraph.
// ---------------------------------------------------------------------------
__global__ __launch_bounds__(256) void spd_levels(
    const u32* __restrict__ inmask, unsigned char* __restrict__ T)
{
    __shared__ u32 F1[256][8], F2[256][8], F3[256][8];
    int i = threadIdx.x;
#pragma unroll
    for (int w = 0; w < 8; w++) { F1[i][w] = inmask[i * 8 + w]; F2[i][w] = 0; F3[i][w] = 0; }
    __syncthreads();
    for (int w = 0; w < 8; w++) {
        u32 m = F1[i][w];
        while (m) {
            int b = __ffs(m) - 1; m &= m - 1;
            int s = w * 32 + b;
#pragma unroll
            for (int j = 0; j < 8; j++) F2[i][j] |= F1[s][j];
        }
    }
    __syncthreads();
    for (int w = 0; w < 8; w++) {
        u32 m = F1[i][w];
        while (m) {
            int b = __ffs(m) - 1; m &= m - 1;
            int s = w * 32 + b;
#pragma unroll
            for (int j = 0; j < 8; j++) F3[i][j] |= F2[s][j];
        }
    }
    __syncthreads();
    for (int w = 0; w < 8; w++) {
        u32 f1 = F1[i][w], f2 = F2[i][w], f3 = F3[i][w];
#pragma unroll
        for (int g = 0; g < 8; g++) {
            u32 word = 0;
#pragma unroll
            for (int b = 0; b < 4; b++) {
                int bit = g * 4 + b;
                u32 k = ((f1 >> bit) & 1u) ? 1u : ((f2 >> bit) & 1u) ? 2u
                       : ((f3 >> bit) & 1u) ? 3u : 4u;
                word |= k << (8 * b);
            }
            *(u32*)(T + i * 256 + w * 32 + g * 4) = word;
        }
    }
}

// ---------------------------------------------------------------------------
// Fused scores+aggregate.  blockIdx = d*16 + src-range p -> each block's K/V
// gather stays inside a 3.2 MB src window; blockIdx%8 == p%8 pins a window
// pair per XCD L2.  2-deep pipeline: src 2 iters ahead, K/V rows 1 ahead.
// ---------------------------------------------------------------------------
__global__ __launch_bounds__(256) void agg_k(
    const u32* __restrict__ ssrc, const u32* __restrict__ bin_off,
    const u16* __restrict__ Qb, const u16* __restrict__ Kb,
    const u16* __restrict__ Vb, const unsigned char* __restrict__ T,
    const float* __restrict__ spd_w, float* __restrict__ out,
    float* __restrict__ denom)
{
    __shared__ float red[4 * 256];
    __shared__ float dred[4 * 8];
    int bid = blockIdx.x;
    int d = bid >> 4;
    int t = threadIdx.x, lane = t & 63, wave = t >> 6;
    int half = lane >> 5, sl = lane & 31;
    int h = sl >> 2;                        // head = (sl*8)>>5
    u32 start = bin_off[bid], end = bin_off[bid + 1];

    uint4 qv = *(const uint4*)(Qb + (size_t)d * 256 + sl * 8);
    float q0,q1,q2,q3,q4,q5,q6,q7;
    unp2(qv.x,q0,q1); unp2(qv.y,q2,q3); unp2(qv.z,q4,q5); unp2(qv.w,q6,q7);
    float sw4 = spd_w[4 * 8 + h];           // spd=4 bias (src>=256, ~98.5%)

    float a0=0.f,a1=0.f,a2=0.f,a3=0.f,a4=0.f,a5=0.f,a6=0.f,a7=0.f,dsum=0.f;

    u32 i = start + (u32)(wave * 2 + half);  // 8 slots, stride 8
    int s_c = 0, s_n = 0;
    uint4 kv_c = make_uint4(0,0,0,0), vv_c = kv_c;
    if (i < end) {
        s_c = (int)ssrc[i];
        kv_c = *(const uint4*)(Kb + (size_t)s_c * 256 + sl * 8);
        vv_c = *(const uint4*)(Vb + (size_t)s_c * 256 + sl * 8);
        if (i + 8 < end) s_n = (int)ssrc[i + 8];
    }
    while (i < end) {
        u32 inx = i + 8;
        uint4 kv_n = kv_c, vv_n = vv_c;
        if (inx < end) {                    // issue next row loads (addr ready)
            kv_n = *(const uint4*)(Kb + (size_t)s_n * 256 + sl * 8);
            vv_n = *(const uint4*)(Vb + (size_t)s_n * 256 + sl * 8);
        }
        int s_nn = (inx + 8 < end) ? (int)ssrc[inx + 8] : 0;
        float k0,k1,k2,k3,k4,k5,k6,k7, v0,v1,v2,v3,v4,v5,v6,v7;
        unp2(kv_c.x,k0,k1); unp2(kv_c.y,k2,k3); unp2(kv_c.z,k4,k5); unp2(kv_c.w,k6,k7);
        unp2(vv_c.x,v0,v1); unp2(vv_c.y,v2,v3); unp2(vv_c.z,v4,v5); unp2(vv_c.w,v6,v7);
        float p = q0*k0+q1*k1+q2*k2+q3*k3+q4*k4+q5*k5+q6*k6+q7*k7;
        p += __shfl_xor(p, 1);
        p += __shfl_xor(p, 2);              // head dot over 4 lanes x 8 ch
        float bias = (s_c < 256) ? spd_w[(int)T[s_c * 256 + d] * 8 + h] : sw4;
        float wgt = __expf(p * 0.17677669529663689f + bias);
        a0 += wgt*v0; a1 += wgt*v1; a2 += wgt*v2; a3 += wgt*v3;
        a4 += wgt*v4; a5 += wgt*v5; a6 += wgt*v6; a7 += wgt*v7;
        if ((sl & 3) == 0) dsum += wgt;
        i = inx; s_c = s_n; s_n = s_nn; kv_c = kv_n; vv_c = vv_n;
    }
    a0 += __shfl_xor(a0,32); a1 += __shfl_xor(a1,32);
    a2 += __shfl_xor(a2,32); a3 += __shfl_xor(a3,32);
    a4 += __shfl_xor(a4,32); a5 += __shfl_xor(a5,32);
    a6 += __shfl_xor(a6,32); a7 += __shfl_xor(a7,32);
    dsum += __shfl_xor(dsum,32);
    if (half == 0) {
        *(float4*)(&red[wave * 256 + sl * 8])     = make_float4(a0,a1,a2,a3);
        *(float4*)(&red[wave * 256 + sl * 8 + 4]) = make_float4(a4,a5,a6,a7);
        if ((sl & 3) == 0) dred[wave * 8 + h] = dsum;
    }
    __syncthreads();
    float sAll = red[t] + red[256 + t] + red[512 + t] + red[768 + t];
    atomicAdd(&out[(size_t)d * 256 + t], sAll);
    if (t < 8) {
        float ds = dred[t] + dred[8 + t] + dred[16 + t] + dred[24 + t];
        atomicAdd(&denom[d * 8 + t], ds);
    }
}

// ---------------------------------------------------------------------------
// LayerNorm: h = out/denom (anchors only) + x.  deg is constant per row ->
// cancels exactly under LN; skipped.  One wave per node, fp32 in/out.
// ---------------------------------------------------------------------------
__global__ __launch_bounds__(256) void ln_k(
    const float* __restrict__ x, const float* __restrict__ out,
    const float* __restrict__ denom, const float* __restrict__ gamma,
    const float* __restrict__ beta, float* __restrict__ y)
{
    int n = blockIdx.x * 4 + (threadIdx.x >> 6);
    if (n >= N_NODES) return;
    int lane = threadIdx.x & 63;
    int ch = lane * 4;
    float4 xv = *(const float4*)(x + (size_t)n * 256 + ch);
    float h0 = xv.x, h1 = xv.y, h2 = xv.z, h3 = xv.w;
    if (n < 256) {
        float den = denom[n * 8 + (lane >> 3)];
        float inv = (den > 0.f) ? 1.0f / den : 0.0f;
        const float* op = out + (size_t)n * 256 + ch;
        h0 += op[0] * inv; h1 += op[1] * inv;
        h2 += op[2] * inv; h3 += op[3] * inv;
    }
    float s = h0 + h1 + h2 + h3;
#pragma unroll
    for (int off = 1; off < 64; off <<= 1) s += __shfl_xor(s, off);
    float mu = s * (1.0f / 256.0f);
    float d0 = h0 - mu, d1 = h1 - mu, d2 = h2 - mu, d3 = h3 - mu;
    float q = d0 * d0 + d1 * d1 + d2 * d2 + d3 * d3;
#pragma unroll
    for (int off = 1; off < 64; off <<= 1) q += __shfl_xor(q, off);
    float rstd = rsqrtf(q * (1.0f / 256.0f) + 1e-5f);
    float4 gv = *(const float4*)(gamma + ch);
    float4 bv = *(const float4*)(beta + ch);
    float4 o;
    o.x = d0 * rstd * gv.x + bv.x;
    o.y = d1 * rstd * gv.y + bv.y;
    o.z = d2 * rstd * gv.z + bv.z;
    o.w = d3 * rstd * gv.w + bv.w;
    *(float4*)(y + (size_t)n * 256 + ch) = o;
}

// ---------------------------------------------------------------------------
extern "C" void kernel_launch(void* const* d_in, const int* in_sizes, int n_in,
                              void* d_out, int out_size, void* d_ws, size_t ws_size,
                              hipStream_t stream)
{
    const float* x     = (const float*)d_in[0];
    const int*   src   = (const int*)d_in[1];
    const int*   dst   = (const int*)d_in[2];
    const float* Wq    = (const float*)d_in[3];
    const float* bq    = (const float*)d_in[4];
    const float* Wk    = (const float*)d_in[5];
    const float* bk    = (const float*)d_in[6];
    const float* Wv    = (const float*)d_in[7];
    const float* bv    = (const float*)d_in[8];
    const float* spd_w = (const float*)d_in[9];
    const float* gamma = (const float*)d_in[10];
    const float* beta  = (const float*)d_in[11];
    float* y = (float*)d_out;

    char* ws = (char*)d_ws;
    // --- zeroed region [0, 294912) ---
    float* denom     = (float*)(ws + 0);          //   8192 B
    float* outf      = (float*)(ws + 8192);       // 262144 B
    u32*   inmask    = (u32*)(ws + 270336);       //   8192 B
    u32*   bintot    = (u32*)(ws + 278528);       //  16384 B (zero ends 294912)
    // --- rest (all written before read) ---
    u32*   bin_off   = (u32*)(ws + 294912);       //  16388 B (pad to 311552)
    unsigned char* T = (unsigned char*)(ws + 311552); // 65536 B -> 377088
    u32*   blockhist = (u32*)(ws + 377088);       // 64*4096*4 = 1 MB -> 1425664
    u32*   blockbase = (u32*)(ws + 1425664);      // 1 MB -> 2474240
    u32*   ssrc      = (u32*)(ws + 2474240);      // 1.2 MB (pad) -> 3676416
    u16*   Qb        = (u16*)(ws + 3676416);      // 128 KB -> 3807488
    u16*   Kb        = (u16*)(ws + 3807488);      // 25.6 MB -> 29407488
    u16*   Vb        = (u16*)(ws + 29407488);     // 25.6 MB -> 55007488
    u16*   Xb        = (u16*)(ws + 55007488);     // 50176*512 B -> 80697600
    u16*   Wb        = (u16*)(ws + 80697600);     // 384 KB (end ~81.1 MB)

    hipMemsetAsync(d_ws, 0, 294912, stream);

    dim3 blk(256);
    cvt_all<<<dim3(12692), blk, 0, stream>>>(x, Wk, Wv, Wq, Xb, Wb);
    gemm3<<<dim3(2346), blk, 0, stream>>>(Xb, Wb, bk, bv, bq, Kb, Vb, Qb);
    hist_k<<<dim3(NB2), blk, 0, stream>>>(src, dst, blockhist, bintot, inmask);
    scan_k<<<dim3(1), blk, 0, stream>>>(bintot, bin_off);
    base_k<<<dim3(16), blk, 0, stream>>>(blockhist, bin_off, blockbase);
    spd_levels<<<dim3(1), blk, 0, stream>>>(inmask, T);
    scatter2_k<<<dim3(NB2), blk, 0, stream>>>(src, dst, blockbase, ssrc);
    agg_k<<<dim3(NBIN), blk, 0, stream>>>(ssrc, bin_off, Qb, Kb, Vb, T, spd_w, outf, denom);
    ln_k<<<dim3((N_NODES + 3) / 4), blk, 0, stream>>>(x, outf, denom, gamma, beta, y);
}

// Round 4
// 204.927 us; speedup vs baseline: 1.3161x; 1.0865x over previous
//
#include <hip/hip_runtime.h>
#include <stdint.h>

#define N_NODES 50000
#define E_EDGES 300000
#define C_CH    256
#define H_HEADS 8
#define NB2     64       // blocks in counting sort
#define CHUNK2  4688     // edges per sort block (64*4688 >= 300000)
#define NBIN    4096     // 256 dst x 16 src-ranges
#define SRCDIV  3125     // 50000/16 -> src-range = s/3125
#define NWG_GEMM 2346    // 391 m-tiles * 6 (mat,nh)

typedef unsigned short u16;
typedef unsigned int   u32;

typedef __attribute__((ext_vector_type(8))) short  v8s;   // 8 bf16 (MFMA A/B frag)
typedef __attribute__((ext_vector_type(4))) float  v4f;   // MFMA C/D frag

__device__ __forceinline__ float bf2f(u16 v) {
    union { u32 u; float f; } x; x.u = ((u32)v) << 16; return x.f;
}
__device__ __forceinline__ u16 f2bf(float f) {
    union { float f; u32 u; } x; x.f = f;
    u32 r = (x.u + 0x7FFFu + ((x.u >> 16) & 1u)) >> 16;
    return (u16)r;
}
__device__ __forceinline__ void unp2(u32 v, float& lo, float& hi) {
    union { u32 u; float f; } x;
    x.u = v << 16; lo = x.f;
    x.u = v & 0xFFFF0000u; hi = x.f;
}
// async global->LDS, 16 B/lane; LDS dest = wave-uniform base + lane*16
__device__ __forceinline__ void gl_lds16(const u16* g, u16* l) {
    __builtin_amdgcn_global_load_lds(
        (const __attribute__((address_space(1))) void*)g,
        (__attribute__((address_space(3))) void*)l, 16, 0, 0);
}
// pack 8 fp32 -> 8 bf16, single 16B LDS store
__device__ __forceinline__ void pack8(const float4 p, const float4 q, u16* dst) {
    u16 tmp[8];
    tmp[0]=f2bf(p.x); tmp[1]=f2bf(p.y); tmp[2]=f2bf(p.z); tmp[3]=f2bf(p.w);
    tmp[4]=f2bf(q.x); tmp[5]=f2bf(q.y); tmp[6]=f2bf(q.z); tmp[7]=f2bf(q.w);
    *(uint4*)dst = *(const uint4*)tmp;
}

// ---------------------------------------------------------------------------
// prep_k: blocks 0..191 convert Wk,Wv,Wq -> bf16 Wb; blocks 192..255 run the
// (dst, src-range) histogram + anchor bitmask.  (X is no longer converted:
// gemm reads fp32 x directly and converts during staging.)
// ---------------------------------------------------------------------------
__global__ __launch_bounds__(256) void prep_k(
    const float* __restrict__ Wk, const float* __restrict__ Wv,
    const float* __restrict__ Wq, u16* __restrict__ Wb,
    const int* __restrict__ src, const int* __restrict__ dst,
    u32* __restrict__ blockhist, u32* __restrict__ bintot,
    u32* __restrict__ inmask)
{
    __shared__ u32 hist[NBIN];
    int t = threadIdx.x, b = blockIdx.x;
    if (b < 192) {
        int m = (b < 64) ? 0 : (b < 128) ? 1 : 2;
        const float* sp = (m == 0) ? Wk : (m == 1) ? Wv : Wq;
        u16* dp = Wb + m * 65536;
        int i = (b & 63) * 1024 + t * 4;
        float4 v = *(const float4*)(sp + i);
        ushort4 o;
        o.x = f2bf(v.x); o.y = f2bf(v.y); o.z = f2bf(v.z); o.w = f2bf(v.w);
        *(ushort4*)(dp + i) = o;
        return;
    }
    int hb = b - 192;                        // 0..63
#pragma unroll
    for (int j = 0; j < 16; j++) hist[t + j * 256] = 0;
    __syncthreads();
    int start = hb * CHUNK2;
    int end = start + CHUNK2; if (end > E_EDGES) end = E_EDGES;
    for (int e = start + t; e < end; e += 256) {
        int d = dst[e], s = src[e];
        atomicAdd(&hist[d * 16 + s / SRCDIV], 1u);     // LDS atomic
        if (s < 256) atomicOr(&inmask[d * 8 + (s >> 5)], 1u << (s & 31));
    }
    __syncthreads();
#pragma unroll
    for (int j = 0; j < 16; j++) {
        int bin = t + j * 256;
        u32 h = hist[bin];
        blockhist[hb * NBIN + bin] = h;
        if (h) atomicAdd(&bintot[bin], h);
    }
}

// ---------------------------------------------------------------------------
// Megakernel: blocks 0..2345 = bf16 GEMM OUT[*,256] = bf16(x) @ W^T + bias
// (128x128 tile, BK=32 dbuf, fp32-A reg-staged with convert — kills the
// 77 MB X-conversion pass; B via global_load_lds).  Block 2346 = scan of
// bintot -> bin_off.  Block 2347 = SPD 3-level reachability.  The 1-block
// tails hide fully under the gemm; LDS (32 KB) is overlaid.
// ---------------------------------------------------------------------------
__global__ __launch_bounds__(256, 4) void gemm3(
    const float* __restrict__ x, const u16* __restrict__ Wb,
    const float* __restrict__ bk, const float* __restrict__ bv,
    const float* __restrict__ bq,
    u16* __restrict__ Kb, u16* __restrict__ Vb, u16* __restrict__ Qb,
    const u32* __restrict__ bintot, u32* __restrict__ bin_off,
    const u32* __restrict__ inmask, unsigned char* __restrict__ T)
{
    __shared__ u16 smem[4][128 * 32];   // A dbuf = smem[0,1], B dbuf = smem[2,3]
    const int t = threadIdx.x;

    if (blockIdx.x >= NWG_GEMM) {
        u32* b32 = (u32*)&smem[0][0];
        if (blockIdx.x == NWG_GEMM) {
            // ---- scan: exclusive scan bintot[4096] -> bin_off[4097] ----
            u32* tsum = b32;
            u32 loc[16]; u32 a = 0;
#pragma unroll
            for (int j = 0; j < 16; j++) { loc[j] = bintot[t * 16 + j]; a += loc[j]; }
            tsum[t] = a;
            __syncthreads();
            for (int off = 1; off < 256; off <<= 1) {
                u32 add = (t >= off) ? tsum[t - off] : 0u;
                __syncthreads();
                tsum[t] += add;
                __syncthreads();
            }
            u32 base = tsum[t] - a;
#pragma unroll
            for (int j = 0; j < 16; j++) { bin_off[t * 16 + j] = base; base += loc[j]; }
            if (t == 255) bin_off[NBIN] = base;
        } else {
            // ---- SPD: 3-level reachability on the 256-anchor subgraph ----
            u32 (*F1)[8] = (u32(*)[8])(b32);
            u32 (*F2)[8] = (u32(*)[8])(b32 + 2048);
            u32 (*F3)[8] = (u32(*)[8])(b32 + 4096);
            int i = t;
#pragma unroll
            for (int w = 0; w < 8; w++) { F1[i][w] = inmask[i * 8 + w]; F2[i][w] = 0; F3[i][w] = 0; }
            __syncthreads();
            for (int w = 0; w < 8; w++) {
                u32 m = F1[i][w];
                while (m) {
                    int b = __ffs(m) - 1; m &= m - 1;
                    int s = w * 32 + b;
#pragma unroll
                    for (int j = 0; j < 8; j++) F2[i][j] |= F1[s][j];
                }
            }
            __syncthreads();
            for (int w = 0; w < 8; w++) {
                u32 m = F1[i][w];
                while (m) {
                    int b = __ffs(m) - 1; m &= m - 1;
                    int s = w * 32 + b;
#pragma unroll
                    for (int j = 0; j < 8; j++) F3[i][j] |= F2[s][j];
                }
            }
            __syncthreads();
            for (int w = 0; w < 8; w++) {
                u32 f1 = F1[i][w], f2 = F2[i][w], f3 = F3[i][w];
#pragma unroll
                for (int g = 0; g < 8; g++) {
                    u32 word = 0;
#pragma unroll
                    for (int b = 0; b < 4; b++) {
                        int bit = g * 4 + b;
                        u32 k = ((f1 >> bit) & 1u) ? 1u : ((f2 >> bit) & 1u) ? 2u
                               : ((f3 >> bit) & 1u) ? 3u : 4u;
                        word |= k << (8 * b);
                    }
                    *(u32*)(T + i * 256 + w * 32 + g * 4) = word;
                }
            }
        }
        return;
    }

    // ---- GEMM ----
    // bijective XCD-chunked swizzle, m-tile-major: all 6 (mat,nh) blocks of
    // an m-tile share one XCD L2 -> fp32 A-panel fetched ~once from HBM.
    const int nwg = NWG_GEMM, q = nwg >> 3, r = nwg & 7;   // q=293, r=2
    int xcd = blockIdx.x & 7, pos = blockIdx.x >> 3;
    int wgid = (xcd < r ? xcd * (q + 1) : r * (q + 1) + (xcd - r) * q) + pos;
    const int mt = wgid / 6, j6 = wgid % 6;
    const int mat = j6 >> 1, nh = j6 & 1;
    const int m0 = mt * 128;
    if (mat == 2 && m0 >= 256) return;           // Q: only first 2 m-tiles
    const int M = (mat == 2) ? 256 : N_NODES;
    const u16* W = Wb + mat * 65536;
    const float* bias = (mat == 0) ? bk : (mat == 1) ? bv : bq;
    u16* OUT = (mat == 0) ? Kb : (mat == 1) ? Vb : Qb;
    const int n0 = nh * 128;

    const int lane = t & 63, w = t >> 6;
    const int quad = lane >> 4, l15 = lane & 15;
    const int mq = w & 1, nq = w >> 1;

    v4f acc[16];
#pragma unroll
    for (int i = 0; i < 16; i++) acc[i] = (v4f)(0.0f);

    // A staging (fp32 -> bf16 via regs): wave w covers rows w*32..+31.
    // lane -> rows {lrow, lrow+16}, fp32 cols (lane&3)*8..+7 per k-tile.
    // Rows clamped to 49999 (x has no pad rows); stores guarded by m<M.
    const int lrow = lane >> 2;               // 0..15
    const int cg   = (lane & 3) * 8;          // fp32 col-group offset
    int rA0 = m0 + w * 32 + lrow; if (rA0 > 49999) rA0 = 49999;
    int rA1 = rA0 + 16;           if (rA1 > 49999) rA1 = 49999;
    const float* gA0 = x + (size_t)rA0 * 256 + cg;
    const float* gA1 = x + (size_t)rA1 * 256 + cg;
    // B staging: global_load_lds, same linear mapping (bf16 weights).
    const u16* gB = W + (size_t)(n0 + w * 32 + lrow) * 256 + (lane & 3) * 8;

    u16* ldsA = &smem[0][(w * 32 + lrow) * 32 + (lane & 3) * 8];

    float4 a00, a01, a10, a11;
#define LOADA(kt) do {                                   \
    a00 = *(const float4*)(gA0 + (kt) * 32);             \
    a01 = *(const float4*)(gA0 + (kt) * 32 + 4);         \
    a10 = *(const float4*)(gA1 + (kt) * 32);             \
    a11 = *(const float4*)(gA1 + (kt) * 32 + 4);         \
} while (0)
#define WRITEA(bi) do {                                  \
    pack8(a00, a01, ldsA + (bi) * 4096);                 \
    pack8(a10, a11, ldsA + (bi) * 4096 + 16 * 32);       \
} while (0)
#define STAGEB(bi, koff) do {                                             \
    gl_lds16(gB + (koff),            &smem[2 + (bi)][(w * 32) * 32]);     \
    gl_lds16(gB + 16 * 256 + (koff), &smem[2 + (bi)][(w * 32 + 16) * 32]);\
} while (0)

    LOADA(0);
    STAGEB(0, 0);
    WRITEA(0);
    __syncthreads();                          // drain prologue (vm + lgkm)
    for (int kt = 0; kt < 8; kt++) {
        const int cur = kt & 1;
        if (kt < 7) { LOADA(kt + 1); STAGEB(cur ^ 1, (kt + 1) * 32); }
        v8s a[4], b[4];
#pragma unroll
        for (int f = 0; f < 4; f++)
            a[f] = *(const v8s*)(&smem[cur][(mq * 64 + f * 16 + l15) * 32 + quad * 8]);
#pragma unroll
        for (int f = 0; f < 4; f++)
            b[f] = *(const v8s*)(&smem[2 + cur][(nq * 64 + f * 16 + l15) * 32 + quad * 8]);
#pragma unroll
        for (int fm = 0; fm < 4; fm++)
#pragma unroll
            for (int fn = 0; fn < 4; fn++)
                acc[fm * 4 + fn] = __builtin_amdgcn_mfma_f32_16x16x32_bf16(
                    a[fm], b[fn], acc[fm * 4 + fn], 0, 0, 0);
        if (kt < 7) WRITEA(cur ^ 1);          // fp32 loads landed under MFMA
        __syncthreads();                      // drains vm (B) + lgkm (A writes)
    }
#undef LOADA
#undef WRITEA
#undef STAGEB

    // Epilogue: stage C+bias into LDS (32 KB = all 4 buffers), coalesced
    // uint4 stores (full 64 B lines -> no write amplification).
    u16* S = &smem[0][0];
#pragma unroll
    for (int fn = 0; fn < 4; fn++) {
        int n = nq * 64 + fn * 16 + l15;
        float bi = bias[n0 + n];
#pragma unroll
        for (int fm = 0; fm < 4; fm++) {
#pragma unroll
            for (int r2 = 0; r2 < 4; r2++) {
                int row = mq * 64 + fm * 16 + quad * 4 + r2;
                S[row * 128 + n] = f2bf(acc[fm * 4 + fn][r2] + bi);
            }
        }
    }
    __syncthreads();
#pragma unroll
    for (int i = 0; i < 8; i++) {
        int c = i * 256 + t;
        int row = c >> 4;
        int m = m0 + row;
        if (m < M)
            *(uint4*)(OUT + (size_t)m * 256 + n0 + (c & 15) * 8) =
                *(const uint4*)(S + c * 8);
    }
}

// ---------------------------------------------------------------------------
// Sort pass 3 (16 blocks): per-(sortblock,bin) base = bin_off + block prefix.
// All 64 histogram values prefetched into regs (one latency), prefix in regs.
// ---------------------------------------------------------------------------
__global__ __launch_bounds__(256) void base_k(
    const u32* __restrict__ blockhist, const u32* __restrict__ bin_off,
    u32* __restrict__ blockbase)
{
    int bin = blockIdx.x * 256 + threadIdx.x;
    u32 h[NB2];
#pragma unroll
    for (int b = 0; b < NB2; b++) h[b] = blockhist[b * NBIN + bin];
    u32 run = bin_off[bin];
#pragma unroll
    for (int b = 0; b < NB2; b++) {
        blockbase[b * NBIN + bin] = run;
        run += h[b];
    }
}

// ---------------------------------------------------------------------------
// Sort pass 4: scatter SRC VALUES into (dst, src-range) buckets (LDS cursors).
// ---------------------------------------------------------------------------
__global__ __launch_bounds__(256) void scatter2_k(
    const int* __restrict__ src, const int* __restrict__ dst,
    const u32* __restrict__ blockbase, u32* __restrict__ ssrc)
{
    __shared__ u32 cur[NBIN];
    int t = threadIdx.x, b = blockIdx.x;
#pragma unroll
    for (int j = 0; j < 16; j++)
        cur[t + j * 256] = blockbase[b * NBIN + t + j * 256];
    __syncthreads();
    int start = b * CHUNK2;
    int end = start + CHUNK2; if (end > E_EDGES) end = E_EDGES;
    for (int e = start + t; e < end; e += 256) {
        int s = src[e];
        int bin = dst[e] * 16 + s / SRCDIV;
        u32 pos = atomicAdd(&cur[bin], 1u);   // LDS atomic
        ssrc[pos] = (u32)s;
    }
}

// ---------------------------------------------------------------------------
// Fused scores+aggregate.  blockIdx = d*16 + src-range p -> each block's K/V
// gather stays inside a 3.2 MB src window; blockIdx%8 == p%8 pins a window
// pair per XCD L2.  2-deep pipeline: src 2 iters ahead, K/V rows 1 ahead.
// ---------------------------------------------------------------------------
__global__ __launch_bounds__(256) void agg_k(
    const u32* __restrict__ ssrc, const u32* __restrict__ bin_off,
    const u16* __restrict__ Qb, const u16* __restrict__ Kb,
    const u16* __restrict__ Vb, const unsigned char* __restrict__ T,
    const float* __restrict__ spd_w, float* __restrict__ out,
    float* __restrict__ denom)
{
    __shared__ float red[4 * 256];
    __shared__ float dred[4 * 8];
    int bid = blockIdx.x;
    int d = bid >> 4;
    int t = threadIdx.x, lane = t & 63, wave = t >> 6;
    int half = lane >> 5, sl = lane & 31;
    int h = sl >> 2;                        // head = (sl*8)>>5
    u32 start = bin_off[bid], end = bin_off[bid + 1];

    uint4 qv = *(const uint4*)(Qb + (size_t)d * 256 + sl * 8);
    float q0,q1,q2,q3,q4,q5,q6,q7;
    unp2(qv.x,q0,q1); unp2(qv.y,q2,q3); unp2(qv.z,q4,q5); unp2(qv.w,q6,q7);
    float sw4 = spd_w[4 * 8 + h];           // spd=4 bias (src>=256, ~98.5%)

    float a0=0.f,a1=0.f,a2=0.f,a3=0.f,a4=0.f,a5=0.f,a6=0.f,a7=0.f,dsum=0.f;

    u32 i = start + (u32)(wave * 2 + half);  // 8 slots, stride 8
    int s_c = 0, s_n = 0;
    uint4 kv_c = make_uint4(0,0,0,0), vv_c = kv_c;
    if (i < end) {
        s_c = (int)ssrc[i];
        kv_c = *(const uint4*)(Kb + (size_t)s_c * 256 + sl * 8);
        vv_c = *(const uint4*)(Vb + (size_t)s_c * 256 + sl * 8);
        if (i + 8 < end) s_n = (int)ssrc[i + 8];
    }
    while (i < end) {
        u32 inx = i + 8;
        uint4 kv_n = kv_c, vv_n = vv_c;
        if (inx < end) {                    // issue next row loads (addr ready)
            kv_n = *(const uint4*)(Kb + (size_t)s_n * 256 + sl * 8);
            vv_n = *(const uint4*)(Vb + (size_t)s_n * 256 + sl * 8);
        }
        int s_nn = (inx + 8 < end) ? (int)ssrc[inx + 8] : 0;
        float k0,k1,k2,k3,k4,k5,k6,k7, v0,v1,v2,v3,v4,v5,v6,v7;
        unp2(kv_c.x,k0,k1); unp2(kv_c.y,k2,k3); unp2(kv_c.z,k4,k5); unp2(kv_c.w,k6,k7);
        unp2(vv_c.x,v0,v1); unp2(vv_c.y,v2,v3); unp2(vv_c.z,v4,v5); unp2(vv_c.w,v6,v7);
        float p = q0*k0+q1*k1+q2*k2+q3*k3+q4*k4+q5*k5+q6*k6+q7*k7;
        p += __shfl_xor(p, 1);
        p += __shfl_xor(p, 2);              // head dot over 4 lanes x 8 ch
        float bias = (s_c < 256) ? spd_w[(int)T[s_c * 256 + d] * 8 + h] : sw4;
        float wgt = __expf(p * 0.17677669529663689f + bias);
        a0 += wgt*v0; a1 += wgt*v1; a2 += wgt*v2; a3 += wgt*v3;
        a4 += wgt*v4; a5 += wgt*v5; a6 += wgt*v6; a7 += wgt*v7;
        if ((sl & 3) == 0) dsum += wgt;
        i = inx; s_c = s_n; s_n = s_nn; kv_c = kv_n; vv_c = vv_n;
    }
    a0 += __shfl_xor(a0,32); a1 += __shfl_xor(a1,32);
    a2 += __shfl_xor(a2,32); a3 += __shfl_xor(a3,32);
    a4 += __shfl_xor(a4,32); a5 += __shfl_xor(a5,32);
    a6 += __shfl_xor(a6,32); a7 += __shfl_xor(a7,32);
    dsum += __shfl_xor(dsum,32);
    if (half == 0) {
        *(float4*)(&red[wave * 256 + sl * 8])     = make_float4(a0,a1,a2,a3);
        *(float4*)(&red[wave * 256 + sl * 8 + 4]) = make_float4(a4,a5,a6,a7);
        if ((sl & 3) == 0) dred[wave * 8 + h] = dsum;
    }
    __syncthreads();
    float sAll = red[t] + red[256 + t] + red[512 + t] + red[768 + t];
    atomicAdd(&out[(size_t)d * 256 + t], sAll);
    if (t < 8) {
        float ds = dred[t] + dred[8 + t] + dred[16 + t] + dred[24 + t];
        atomicAdd(&denom[d * 8 + t], ds);
    }
}

// ---------------------------------------------------------------------------
// LayerNorm: h = out/denom (anchors only) + x.  deg is constant per row ->
// cancels exactly under LN; skipped.  One wave per node, fp32 in/out.
// ---------------------------------------------------------------------------
__global__ __launch_bounds__(256) void ln_k(
    const float* __restrict__ x, const float* __restrict__ out,
    const float* __restrict__ denom, const float* __restrict__ gamma,
    const float* __restrict__ beta, float* __restrict__ y)
{
    int n = blockIdx.x * 4 + (threadIdx.x >> 6);
    if (n >= N_NODES) return;
    int lane = threadIdx.x & 63;
    int ch = lane * 4;
    float4 xv = *(const float4*)(x + (size_t)n * 256 + ch);
    float h0 = xv.x, h1 = xv.y, h2 = xv.z, h3 = xv.w;
    if (n < 256) {
        float den = denom[n * 8 + (lane >> 3)];
        float inv = (den > 0.f) ? 1.0f / den : 0.0f;
        const float* op = out + (size_t)n * 256 + ch;
        h0 += op[0] * inv; h1 += op[1] * inv;
        h2 += op[2] * inv; h3 += op[3] * inv;
    }
    float s = h0 + h1 + h2 + h3;
#pragma unroll
    for (int off = 1; off < 64; off <<= 1) s += __shfl_xor(s, off);
    float mu = s * (1.0f / 256.0f);
    float d0 = h0 - mu, d1 = h1 - mu, d2 = h2 - mu, d3 = h3 - mu;
    float q = d0 * d0 + d1 * d1 + d2 * d2 + d3 * d3;
#pragma unroll
    for (int off = 1; off < 64; off <<= 1) q += __shfl_xor(q, off);
    float rstd = rsqrtf(q * (1.0f / 256.0f) + 1e-5f);
    float4 gv = *(const float4*)(gamma + ch);
    float4 bv = *(const float4*)(beta + ch);
    float4 o;
    o.x = d0 * rstd * gv.x + bv.x;
    o.y = d1 * rstd * gv.y + bv.y;
    o.z = d2 * rstd * gv.z + bv.z;
    o.w = d3 * rstd * gv.w + bv.w;
    *(float4*)(y + (size_t)n * 256 + ch) = o;
}

// ---------------------------------------------------------------------------
extern "C" void kernel_launch(void* const* d_in, const int* in_sizes, int n_in,
                              void* d_out, int out_size, void* d_ws, size_t ws_size,
                              hipStream_t stream)
{
    const float* x     = (const float*)d_in[0];
    const int*   src   = (const int*)d_in[1];
    const int*   dst   = (const int*)d_in[2];
    const float* Wq    = (const float*)d_in[3];
    const float* bq    = (const float*)d_in[4];
    const float* Wk    = (const float*)d_in[5];
    const float* bk    = (const float*)d_in[6];
    const float* Wv    = (const float*)d_in[7];
    const float* bv    = (const float*)d_in[8];
    const float* spd_w = (const float*)d_in[9];
    const float* gamma = (const float*)d_in[10];
    const float* beta  = (const float*)d_in[11];
    float* y = (float*)d_out;

    char* ws = (char*)d_ws;
    // --- zeroed region [0, 294912) ---
    float* denom     = (float*)(ws + 0);          //   8192 B
    float* outf      = (float*)(ws + 8192);       // 262144 B
    u32*   inmask    = (u32*)(ws + 270336);       //   8192 B
    u32*   bintot    = (u32*)(ws + 278528);       //  16384 B (zero ends 294912)
    // --- rest (all written before read) ---
    u32*   bin_off   = (u32*)(ws + 294912);       //  16388 B (pad to 311552)
    unsigned char* T = (unsigned char*)(ws + 311552); // 65536 B -> 377088
    u32*   blockhist = (u32*)(ws + 377088);       // 64*4096*4 = 1 MB -> 1425664
    u32*   blockbase = (u32*)(ws + 1425664);      // 1 MB -> 2474240
    u32*   ssrc      = (u32*)(ws + 2474240);      // 1.2 MB (pad) -> 3676416
    u16*   Qb        = (u16*)(ws + 3676416);      // 128 KB -> 3807488
    u16*   Kb        = (u16*)(ws + 3807488);      // 25.6 MB -> 29407488
    u16*   Vb        = (u16*)(ws + 29407488);     // 25.6 MB -> 55007488
    u16*   Wb        = (u16*)(ws + 55007488);     // 384 KB (end ~55.4 MB)

    hipMemsetAsync(d_ws, 0, 294912, stream);

    dim3 blk(256);
    prep_k<<<dim3(256), blk, 0, stream>>>(Wk, Wv, Wq, Wb, src, dst,
                                          blockhist, bintot, inmask);
    gemm3<<<dim3(NWG_GEMM + 2), blk, 0, stream>>>(x, Wb, bk, bv, bq,
                                                  Kb, Vb, Qb, bintot, bin_off,
                                                  inmask, T);
    base_k<<<dim3(16), blk, 0, stream>>>(blockhist, bin_off, blockbase);
    scatter2_k<<<dim3(NB2), blk, 0, stream>>>(src, dst, blockbase, ssrc);
    agg_k<<<dim3(NBIN), blk, 0, stream>>>(ssrc, bin_off, Qb, Kb, Vb, T, spd_w, outf, denom);
    ln_k<<<dim3((N_NODES + 3) / 4), blk, 0, stream>>>(x, outf, denom, gamma, beta, y);
}